// Round 7
// baseline (332.370 us; speedup 1.0000x reference)
//
#include <hip/hip_runtime.h>
#include <hip/hip_bf16.h>

// Packed varlen causal GQA attention (flash-style), MI355X gfx950.
// Q [T,H,D] f32, K/V [T,G,D] f32, cu_seqlens [9] int32 -> O [T,H,D] f32.
// T=4096, H=16, G=4, D=128, SCALE=1/sqrt(128).
//
// R7: in-block 2-way K-split. 512 threads = 8 waves: waves 0-3 (split 0)
// handle heads g*4+0..3 over the first half of the key span; waves 4-7
// (split 1) same heads over the second half. Independent (m,l,O) per split,
// merged through LDS at the end. Halves the per-block critical path and
// doubles resident waves (occupancy was 7.9% -- parallelism-starved).
// MFMA layouts (HW-verified m89/m91/m118-m122), 16x16x32_bf16:
//   A[m=lane&15][k=quad*8+j], B[k=quad*8+j][n=lane&15],
//   C/D: row m = quad*4+reg, col n = lane&15.

#define T_TOK 4096
#define NH    16
#define NG    4
#define HD    128
#define NCU   9

typedef short          short8_t __attribute__((ext_vector_type(8)));
typedef float          float4_t __attribute__((ext_vector_type(4)));
typedef unsigned int   uint2_t  __attribute__((ext_vector_type(2)));
typedef unsigned short ushort;

static __device__ inline unsigned pack2(float a, float b) {
    __hip_bfloat162 h = __float22bfloat162_rn(make_float2(a, b));
    union { __hip_bfloat162 h; unsigned u; } c; c.h = h;
    return c.u;
}
static __device__ inline short8_t cvt8(float4_t lo, float4_t hi) {
    union { unsigned u[4]; short8_t s; } r;
    r.u[0] = pack2(lo[0], lo[1]); r.u[1] = pack2(lo[2], lo[3]);
    r.u[2] = pack2(hi[0], hi[1]); r.u[3] = pack2(hi[2], hi[3]);
    return r.s;
}

__global__ __launch_bounds__(512, 4) void attn_fwd(
    const float* __restrict__ Q,
    const float* __restrict__ K,
    const float* __restrict__ V,
    const int*   __restrict__ cu,
    float*       __restrict__ O)
{
    // Carved shared memory (explicit offsets; combine phase reuses it):
    //   Ks[2][32][136] ushort : 17408 B  @ 0
    //   Vt[2][128][40] ushort : 20480 B  @ 17408
    //   pb[8][2][16][40]ushort: 20480 B  @ 37888   (total 58368 B)
    __shared__ __align__(16) unsigned char smem[58368];
    ushort (*Ks)[32][136]   = (ushort (*)[32][136])smem;
    ushort (*Vt)[128][40]   = (ushort (*)[128][40])(smem + 17408);
    ushort (*pb)[2][16][40] = (ushort (*)[2][16][40])(smem + 37888);

    const int qtile = (int)gridDim.x - 1 - (int)blockIdx.x; // big tiles first
    const int g     = blockIdx.y;
    const int tid   = threadIdx.x;
    const int wave  = tid >> 6;          // 0..7
    const int split = wave >> 2;         // 0..1 (key-range half)
    const int hw    = wave & 3;
    const int lane  = tid & 63;
    const int h     = g * 4 + hw;        // query head; h//4 == g (jnp.repeat)
    const int col   = lane & 15;
    const int quad  = lane >> 4;

    const int qbase = qtile * 32;        // 32 q rows per block
    const int qq[2] = { qbase + col, qbase + 16 + col };

    // segment starts: per-lane per-tile, and block-uniform for k0
    int seg_start[2] = {0, 0}, seg0 = 0;
    #pragma unroll
    for (int j = 1; j < NCU; ++j) {
        int cj = cu[j];
        if (cj <= qq[0])  seg_start[0] = cj;
        if (cj <= qq[1])  seg_start[1] = cj;
        if (cj <= qbase)  seg0         = cj;
    }
    const int k0   = seg0 & ~31;
    const int nblk = (qbase + 32 - k0) >> 5;   // 32-key blocks in span
    const int nb0  = (nblk + 1) >> 1;          // iterations per split
    const int kstart = k0 + split * nb0 * 32;  // this split's range start

    // Q fragments (B-operand of S^T = K*Q^T), 2 tiles. dim = c*32+quad*8+j.
    short8_t qf[2][4];
    #pragma unroll
    for (int tt = 0; tt < 2; ++tt) {
        const float* qp = Q + ((long)qq[tt] * NH + h) * HD + quad * 8;
        #pragma unroll
        for (int c = 0; c < 4; ++c)
            qf[tt][c] = cvt8(*(const float4_t*)(qp + c * 32),
                             *(const float4_t*)(qp + c * 32 + 4));
    }

    float4_t oacc[2][8];
    #pragma unroll
    for (int tt = 0; tt < 2; ++tt)
        #pragma unroll
        for (int dt = 0; dt < 8; ++dt) oacc[tt][dt] = (float4_t){0.f, 0.f, 0.f, 0.f};

    float m_run[2] = {-10000.0f, -10000.0f};
    float l_run[2] = {0.0f, 0.0f};
    const float c_scale = 0.08838834764831845f * 1.4426950408889634f; // SCALE*log2e

    // staging thread mapping (256 threads per split, 32 keys x 128 dims)
    const int stid = tid & 255;
    const int ki  = stid >> 3;           // K: key-in-tile
    const int ch  = (stid & 7) * 16;     // K: dim chunk
    const int kp2 = (stid & 15) * 2;     // V: key pair
    const int dc  = (stid >> 4) * 8;     // V: dim chunk

    float4_t kreg[4], vreg[4];
    {
        int key = kstart + ki; if (key > T_TOK - 1) key = T_TOK - 1;
        const float* kp = K + ((long)key * NG + g) * HD + ch;
        kreg[0] = *(const float4_t*)kp;       kreg[1] = *(const float4_t*)(kp + 4);
        kreg[2] = *(const float4_t*)(kp + 8); kreg[3] = *(const float4_t*)(kp + 12);
        int key0 = kstart + kp2;     if (key0 > T_TOK - 1) key0 = T_TOK - 1;
        int key1 = kstart + kp2 + 1; if (key1 > T_TOK - 1) key1 = T_TOK - 1;
        const float* v0 = V + ((long)key0 * NG + g) * HD + dc;
        const float* v1 = V + ((long)key1 * NG + g) * HD + dc;
        vreg[0] = *(const float4_t*)v0; vreg[1] = *(const float4_t*)(v0 + 4);
        vreg[2] = *(const float4_t*)v1; vreg[3] = *(const float4_t*)(v1 + 4);
    }

    for (int it = 0; it < nb0; ++it) {
        const int kb = kstart + it * 32;
        __syncthreads();   // previous iter's LDS reads complete

        // ---- write prefetched K/V regs -> LDS (bf16), own split's buffers ----
        *(short8_t*)&Ks[split][ki][ch]     = cvt8(kreg[0], kreg[1]);
        *(short8_t*)&Ks[split][ki][ch + 8] = cvt8(kreg[2], kreg[3]);
        #pragma unroll
        for (int d = 0; d < 4; ++d) {
            *(unsigned*)&Vt[split][dc + d][kp2]     = pack2(vreg[0][d], vreg[2][d]);
            *(unsigned*)&Vt[split][dc + 4 + d][kp2] = pack2(vreg[1][d], vreg[3][d]);
        }
        __syncthreads();

        // ---- prefetch next 32-key block (in flight during compute) ----
        {
            int nb = kb + 32;
            int key = nb + ki; if (key > T_TOK - 1) key = T_TOK - 1;
            const float* kp = K + ((long)key * NG + g) * HD + ch;
            kreg[0] = *(const float4_t*)kp;       kreg[1] = *(const float4_t*)(kp + 4);
            kreg[2] = *(const float4_t*)(kp + 8); kreg[3] = *(const float4_t*)(kp + 12);
            int key0 = nb + kp2;     if (key0 > T_TOK - 1) key0 = T_TOK - 1;
            int key1 = nb + kp2 + 1; if (key1 > T_TOK - 1) key1 = T_TOK - 1;
            const float* v0 = V + ((long)key0 * NG + g) * HD + dc;
            const float* v1 = V + ((long)key1 * NG + g) * HD + dc;
            vreg[0] = *(const float4_t*)v0; vreg[1] = *(const float4_t*)(v0 + 4);
            vreg[2] = *(const float4_t*)v1; vreg[3] = *(const float4_t*)(v1 + 4);
        }

        // ---- S^T tiles: 8 K-frag reads feed 16 MFMAs (2 q-tiles) ----
        float4_t st[2][2];
        #pragma unroll
        for (int tt = 0; tt < 2; ++tt)
            #pragma unroll
            for (int t = 0; t < 2; ++t) st[tt][t] = (float4_t){0.f, 0.f, 0.f, 0.f};
        #pragma unroll
        for (int c = 0; c < 4; ++c) {
            short8_t kf0 = *(const short8_t*)&Ks[split][col][c * 32 + quad * 8];
            short8_t kf1 = *(const short8_t*)&Ks[split][16 + col][c * 32 + quad * 8];
            st[0][0] = __builtin_amdgcn_mfma_f32_16x16x32_bf16(kf0, qf[0][c], st[0][0], 0, 0, 0);
            st[0][1] = __builtin_amdgcn_mfma_f32_16x16x32_bf16(kf1, qf[0][c], st[0][1], 0, 0, 0);
            st[1][0] = __builtin_amdgcn_mfma_f32_16x16x32_bf16(kf0, qf[1][c], st[1][0], 0, 0, 0);
            st[1][1] = __builtin_amdgcn_mfma_f32_16x16x32_bf16(kf1, qf[1][c], st[1][1], 0, 0, 0);
        }

        // ---- mask + online softmax per q-tile (log2 domain) ----
        #pragma unroll
        for (int tt = 0; tt < 2; ++tt) {
            float tv[8];
            #pragma unroll
            for (int t = 0; t < 2; ++t)
                #pragma unroll
                for (int r = 0; r < 4; ++r) {
                    int key = kb + 16 * t + quad * 4 + r;
                    bool valid = (key <= qq[tt]) && (key >= seg_start[tt]);
                    tv[t * 4 + r] = valid ? st[tt][t][r] * c_scale : -30000.0f;
                }
            float tmax = tv[0];
            #pragma unroll
            for (int i = 1; i < 8; ++i) tmax = fmaxf(tmax, tv[i]);
            tmax = fmaxf(tmax, __shfl_xor(tmax, 16));
            tmax = fmaxf(tmax, __shfl_xor(tmax, 32));
            const float m_new = fmaxf(m_run[tt], tmax);
            const float alpha = __builtin_exp2f(m_run[tt] - m_new);
            float p[8], ps = 0.f;
            #pragma unroll
            for (int i = 0; i < 8; ++i) { p[i] = __builtin_exp2f(tv[i] - m_new); ps += p[i]; }
            ps += __shfl_xor(ps, 16);
            ps += __shfl_xor(ps, 32);
            l_run[tt] = l_run[tt] * alpha + ps;
            m_run[tt] = m_new;
            #pragma unroll
            for (int dt = 0; dt < 8; ++dt) oacc[tt][dt] *= alpha;

            uint2_t w0; w0.x = pack2(p[0], p[1]); w0.y = pack2(p[2], p[3]);
            uint2_t w1; w1.x = pack2(p[4], p[5]); w1.y = pack2(p[6], p[7]);
            *(uint2_t*)&pb[wave][tt][col][quad * 4]      = w0;
            *(uint2_t*)&pb[wave][tt][col][16 + quad * 4] = w1;
        }
        short8_t pf0 = *(const short8_t*)&pb[wave][0][col][quad * 8];
        short8_t pf1 = *(const short8_t*)&pb[wave][1][col][quad * 8];

        // ---- O^T += V^T * P^T : 8 V-frag reads feed 16 MFMAs ----
        #pragma unroll
        for (int dt = 0; dt < 8; ++dt) {
            short8_t vf = *(const short8_t*)&Vt[split][dt * 16 + col][quad * 8];
            oacc[0][dt] = __builtin_amdgcn_mfma_f32_16x16x32_bf16(vf, pf0, oacc[0][dt], 0, 0, 0);
            oacc[1][dt] = __builtin_amdgcn_mfma_f32_16x16x32_bf16(vf, pf1, oacc[1][dt], 0, 0, 0);
        }
    }

    // ---- merge split1's (m,l,O) into split0 via LDS (region reuse) ----
    float* Ob = (float*)smem;                  // [4 heads][16 q][132] floats
    float* cm = (float*)(smem + 34816);        // 64 floats per pass
    float* cl = (float*)(smem + 35840);
    #pragma unroll
    for (int tt = 0; tt < 2; ++tt) {
        __syncthreads();
        if (split == 1) {
            if (quad == 0) { cm[hw * 16 + col] = m_run[tt]; cl[hw * 16 + col] = l_run[tt]; }
            float* ob = Ob + (hw * 16 + col) * 132;
            #pragma unroll
            for (int dt = 0; dt < 8; ++dt)
                *(float4_t*)(ob + dt * 16 + quad * 4) = oacc[tt][dt];
        }
        __syncthreads();
        if (split == 0) {
            const float m1 = cm[hw * 16 + col], l1 = cl[hw * 16 + col];
            const float m  = fmaxf(m_run[tt], m1);
            const float a0 = __builtin_exp2f(m_run[tt] - m);
            const float a1 = __builtin_exp2f(m1 - m);
            const float* ob = Ob + (hw * 16 + col) * 132;
            #pragma unroll
            for (int dt = 0; dt < 8; ++dt) {
                float4_t o1 = *(const float4_t*)(ob + dt * 16 + quad * 4);
                oacc[tt][dt] = oacc[tt][dt] * a0 + o1 * a1;
            }
            l_run[tt] = l_run[tt] * a0 + l1 * a1;
        }
    }

    // ---- epilogue (split 0 only): O[q][h][dim=dt*16+quad*4+r] = oacc/l ----
    if (split == 0) {
        #pragma unroll
        for (int tt = 0; tt < 2; ++tt) {
            const float inv_l = 1.0f / l_run[tt];
            float* op = O + ((long)qq[tt] * NH + h) * HD + quad * 4;
            #pragma unroll
            for (int dt = 0; dt < 8; ++dt) {
                float4_t ov;
                #pragma unroll
                for (int r = 0; r < 4; ++r) ov[r] = oacc[tt][dt][r] * inv_l;
                *(float4_t*)(op + dt * 16) = ov;
            }
        }
    }
}

extern "C" void kernel_launch(void* const* d_in, const int* in_sizes, int n_in,
                              void* d_out, int out_size, void* d_ws, size_t ws_size,
                              hipStream_t stream) {
    const float* Q  = (const float*)d_in[0];
    const float* K  = (const float*)d_in[1];
    const float* V  = (const float*)d_in[2];
    const int*   cu = (const int*)d_in[3];
    float*       O  = (float*)d_out;
    dim3 grid(T_TOK / 32, NG);
    attn_fwd<<<grid, 512, 0, stream>>>(Q, K, V, cu, O);
}

// Round 8
// 219.532 us; speedup vs baseline: 1.5140x; 1.5140x over previous
//
#include <hip/hip_runtime.h>
#include <hip/hip_bf16.h>

// Packed varlen causal GQA attention (flash-style), MI355X gfx950.
// Q [T,H,D] f32, K/V [T,G,D] f32, cu_seqlens [9] int32 -> O [T,H,D] f32.
// T=4096, H=16, G=4, D=128, SCALE=1/sqrt(128).
//
// R8 = R7 with ONE change: __launch_bounds__(512) (no min-blocks arg).
// R7's (512,4) second arg acted as min-BLOCKS-per-CU (CUDA semantics):
// 4 blocks x 8 waves = 8 waves/SIMD -> 64 VGPRs -> massive scratch spills
// (VGPR_Count=64, FETCH 75.8->224MB, WRITE 32.8->77.8MB). Unconstrained,
// the same per-wave state compiled to 120 VGPRs in R6 with no spill.
//
// Structure: in-block 2-way K-split. 512 threads = 8 waves: waves 0-3
// (split 0) handle heads g*4+0..3 over the first half of the key span;
// waves 4-7 (split 1) same heads over the second half. Independent
// (m,l,O) per split, merged through LDS at the end.
// MFMA layouts (HW-verified m89/m91/m118-m122), 16x16x32_bf16:
//   A[m=lane&15][k=quad*8+j], B[k=quad*8+j][n=lane&15],
//   C/D: row m = quad*4+reg, col n = lane&15.

#define T_TOK 4096
#define NH    16
#define NG    4
#define HD    128
#define NCU   9

typedef short          short8_t __attribute__((ext_vector_type(8)));
typedef float          float4_t __attribute__((ext_vector_type(4)));
typedef unsigned int   uint2_t  __attribute__((ext_vector_type(2)));
typedef unsigned short ushort;

static __device__ inline unsigned pack2(float a, float b) {
    __hip_bfloat162 h = __float22bfloat162_rn(make_float2(a, b));
    union { __hip_bfloat162 h; unsigned u; } c; c.h = h;
    return c.u;
}
static __device__ inline short8_t cvt8(float4_t lo, float4_t hi) {
    union { unsigned u[4]; short8_t s; } r;
    r.u[0] = pack2(lo[0], lo[1]); r.u[1] = pack2(lo[2], lo[3]);
    r.u[2] = pack2(hi[0], hi[1]); r.u[3] = pack2(hi[2], hi[3]);
    return r.s;
}

__global__ __launch_bounds__(512) void attn_fwd(
    const float* __restrict__ Q,
    const float* __restrict__ K,
    const float* __restrict__ V,
    const int*   __restrict__ cu,
    float*       __restrict__ O)
{
    // Carved shared memory (explicit offsets; combine phase reuses it):
    //   Ks[2][32][136] ushort : 17408 B  @ 0
    //   Vt[2][128][40] ushort : 20480 B  @ 17408
    //   pb[8][2][16][40]ushort: 20480 B  @ 37888   (total 58368 B)
    __shared__ __align__(16) unsigned char smem[58368];
    ushort (*Ks)[32][136]   = (ushort (*)[32][136])smem;
    ushort (*Vt)[128][40]   = (ushort (*)[128][40])(smem + 17408);
    ushort (*pb)[2][16][40] = (ushort (*)[2][16][40])(smem + 37888);

    const int qtile = (int)gridDim.x - 1 - (int)blockIdx.x; // big tiles first
    const int g     = blockIdx.y;
    const int tid   = threadIdx.x;
    const int wave  = tid >> 6;          // 0..7
    const int split = wave >> 2;         // 0..1 (key-range half)
    const int hw    = wave & 3;
    const int lane  = tid & 63;
    const int h     = g * 4 + hw;        // query head; h//4 == g (jnp.repeat)
    const int col   = lane & 15;
    const int quad  = lane >> 4;

    const int qbase = qtile * 32;        // 32 q rows per block
    const int qq[2] = { qbase + col, qbase + 16 + col };

    // segment starts: per-lane per-tile, and block-uniform for k0
    int seg_start[2] = {0, 0}, seg0 = 0;
    #pragma unroll
    for (int j = 1; j < NCU; ++j) {
        int cj = cu[j];
        if (cj <= qq[0])  seg_start[0] = cj;
        if (cj <= qq[1])  seg_start[1] = cj;
        if (cj <= qbase)  seg0         = cj;
    }
    const int k0   = seg0 & ~31;
    const int nblk = (qbase + 32 - k0) >> 5;   // 32-key blocks in span
    const int nb0  = (nblk + 1) >> 1;          // iterations per split
    const int kstart = k0 + split * nb0 * 32;  // this split's range start

    // Q fragments (B-operand of S^T = K*Q^T), 2 tiles. dim = c*32+quad*8+j.
    short8_t qf[2][4];
    #pragma unroll
    for (int tt = 0; tt < 2; ++tt) {
        const float* qp = Q + ((long)qq[tt] * NH + h) * HD + quad * 8;
        #pragma unroll
        for (int c = 0; c < 4; ++c)
            qf[tt][c] = cvt8(*(const float4_t*)(qp + c * 32),
                             *(const float4_t*)(qp + c * 32 + 4));
    }

    float4_t oacc[2][8];
    #pragma unroll
    for (int tt = 0; tt < 2; ++tt)
        #pragma unroll
        for (int dt = 0; dt < 8; ++dt) oacc[tt][dt] = (float4_t){0.f, 0.f, 0.f, 0.f};

    float m_run[2] = {-10000.0f, -10000.0f};
    float l_run[2] = {0.0f, 0.0f};
    const float c_scale = 0.08838834764831845f * 1.4426950408889634f; // SCALE*log2e

    // staging thread mapping (256 threads per split, 32 keys x 128 dims)
    const int stid = tid & 255;
    const int ki  = stid >> 3;           // K: key-in-tile
    const int ch  = (stid & 7) * 16;     // K: dim chunk
    const int kp2 = (stid & 15) * 2;     // V: key pair
    const int dc  = (stid >> 4) * 8;     // V: dim chunk

    float4_t kreg[4], vreg[4];
    {
        int key = kstart + ki; if (key > T_TOK - 1) key = T_TOK - 1;
        const float* kp = K + ((long)key * NG + g) * HD + ch;
        kreg[0] = *(const float4_t*)kp;       kreg[1] = *(const float4_t*)(kp + 4);
        kreg[2] = *(const float4_t*)(kp + 8); kreg[3] = *(const float4_t*)(kp + 12);
        int key0 = kstart + kp2;     if (key0 > T_TOK - 1) key0 = T_TOK - 1;
        int key1 = kstart + kp2 + 1; if (key1 > T_TOK - 1) key1 = T_TOK - 1;
        const float* v0 = V + ((long)key0 * NG + g) * HD + dc;
        const float* v1 = V + ((long)key1 * NG + g) * HD + dc;
        vreg[0] = *(const float4_t*)v0; vreg[1] = *(const float4_t*)(v0 + 4);
        vreg[2] = *(const float4_t*)v1; vreg[3] = *(const float4_t*)(v1 + 4);
    }

    for (int it = 0; it < nb0; ++it) {
        const int kb = kstart + it * 32;
        __syncthreads();   // previous iter's LDS reads complete

        // ---- write prefetched K/V regs -> LDS (bf16), own split's buffers ----
        *(short8_t*)&Ks[split][ki][ch]     = cvt8(kreg[0], kreg[1]);
        *(short8_t*)&Ks[split][ki][ch + 8] = cvt8(kreg[2], kreg[3]);
        #pragma unroll
        for (int d = 0; d < 4; ++d) {
            *(unsigned*)&Vt[split][dc + d][kp2]     = pack2(vreg[0][d], vreg[2][d]);
            *(unsigned*)&Vt[split][dc + 4 + d][kp2] = pack2(vreg[1][d], vreg[3][d]);
        }
        __syncthreads();

        // ---- prefetch next 32-key block (in flight during compute) ----
        {
            int nb = kb + 32;
            int key = nb + ki; if (key > T_TOK - 1) key = T_TOK - 1;
            const float* kp = K + ((long)key * NG + g) * HD + ch;
            kreg[0] = *(const float4_t*)kp;       kreg[1] = *(const float4_t*)(kp + 4);
            kreg[2] = *(const float4_t*)(kp + 8); kreg[3] = *(const float4_t*)(kp + 12);
            int key0 = nb + kp2;     if (key0 > T_TOK - 1) key0 = T_TOK - 1;
            int key1 = nb + kp2 + 1; if (key1 > T_TOK - 1) key1 = T_TOK - 1;
            const float* v0 = V + ((long)key0 * NG + g) * HD + dc;
            const float* v1 = V + ((long)key1 * NG + g) * HD + dc;
            vreg[0] = *(const float4_t*)v0; vreg[1] = *(const float4_t*)(v0 + 4);
            vreg[2] = *(const float4_t*)v1; vreg[3] = *(const float4_t*)(v1 + 4);
        }

        // ---- S^T tiles: 8 K-frag reads feed 16 MFMAs (2 q-tiles) ----
        float4_t st[2][2];
        #pragma unroll
        for (int tt = 0; tt < 2; ++tt)
            #pragma unroll
            for (int t = 0; t < 2; ++t) st[tt][t] = (float4_t){0.f, 0.f, 0.f, 0.f};
        #pragma unroll
        for (int c = 0; c < 4; ++c) {
            short8_t kf0 = *(const short8_t*)&Ks[split][col][c * 32 + quad * 8];
            short8_t kf1 = *(const short8_t*)&Ks[split][16 + col][c * 32 + quad * 8];
            st[0][0] = __builtin_amdgcn_mfma_f32_16x16x32_bf16(kf0, qf[0][c], st[0][0], 0, 0, 0);
            st[0][1] = __builtin_amdgcn_mfma_f32_16x16x32_bf16(kf1, qf[0][c], st[0][1], 0, 0, 0);
            st[1][0] = __builtin_amdgcn_mfma_f32_16x16x32_bf16(kf0, qf[1][c], st[1][0], 0, 0, 0);
            st[1][1] = __builtin_amdgcn_mfma_f32_16x16x32_bf16(kf1, qf[1][c], st[1][1], 0, 0, 0);
        }

        // ---- mask + online softmax per q-tile (log2 domain) ----
        #pragma unroll
        for (int tt = 0; tt < 2; ++tt) {
            float tv[8];
            #pragma unroll
            for (int t = 0; t < 2; ++t)
                #pragma unroll
                for (int r = 0; r < 4; ++r) {
                    int key = kb + 16 * t + quad * 4 + r;
                    bool valid = (key <= qq[tt]) && (key >= seg_start[tt]);
                    tv[t * 4 + r] = valid ? st[tt][t][r] * c_scale : -30000.0f;
                }
            float tmax = tv[0];
            #pragma unroll
            for (int i = 1; i < 8; ++i) tmax = fmaxf(tmax, tv[i]);
            tmax = fmaxf(tmax, __shfl_xor(tmax, 16));
            tmax = fmaxf(tmax, __shfl_xor(tmax, 32));
            const float m_new = fmaxf(m_run[tt], tmax);
            const float alpha = __builtin_exp2f(m_run[tt] - m_new);
            float p[8], ps = 0.f;
            #pragma unroll
            for (int i = 0; i < 8; ++i) { p[i] = __builtin_exp2f(tv[i] - m_new); ps += p[i]; }
            ps += __shfl_xor(ps, 16);
            ps += __shfl_xor(ps, 32);
            l_run[tt] = l_run[tt] * alpha + ps;
            m_run[tt] = m_new;
            #pragma unroll
            for (int dt = 0; dt < 8; ++dt) oacc[tt][dt] *= alpha;

            uint2_t w0; w0.x = pack2(p[0], p[1]); w0.y = pack2(p[2], p[3]);
            uint2_t w1; w1.x = pack2(p[4], p[5]); w1.y = pack2(p[6], p[7]);
            *(uint2_t*)&pb[wave][tt][col][quad * 4]      = w0;
            *(uint2_t*)&pb[wave][tt][col][16 + quad * 4] = w1;
        }
        short8_t pf0 = *(const short8_t*)&pb[wave][0][col][quad * 8];
        short8_t pf1 = *(const short8_t*)&pb[wave][1][col][quad * 8];

        // ---- O^T += V^T * P^T : 8 V-frag reads feed 16 MFMAs ----
        #pragma unroll
        for (int dt = 0; dt < 8; ++dt) {
            short8_t vf = *(const short8_t*)&Vt[split][dt * 16 + col][quad * 8];
            oacc[0][dt] = __builtin_amdgcn_mfma_f32_16x16x32_bf16(vf, pf0, oacc[0][dt], 0, 0, 0);
            oacc[1][dt] = __builtin_amdgcn_mfma_f32_16x16x32_bf16(vf, pf1, oacc[1][dt], 0, 0, 0);
        }
    }

    // ---- merge split1's (m,l,O) into split0 via LDS (region reuse) ----
    float* Ob = (float*)smem;                  // [4 heads][16 q][132] floats
    float* cm = (float*)(smem + 34816);        // 64 floats per pass
    float* cl = (float*)(smem + 35840);
    #pragma unroll
    for (int tt = 0; tt < 2; ++tt) {
        __syncthreads();
        if (split == 1) {
            if (quad == 0) { cm[hw * 16 + col] = m_run[tt]; cl[hw * 16 + col] = l_run[tt]; }
            float* ob = Ob + (hw * 16 + col) * 132;
            #pragma unroll
            for (int dt = 0; dt < 8; ++dt)
                *(float4_t*)(ob + dt * 16 + quad * 4) = oacc[tt][dt];
        }
        __syncthreads();
        if (split == 0) {
            const float m1 = cm[hw * 16 + col], l1 = cl[hw * 16 + col];
            const float m  = fmaxf(m_run[tt], m1);
            const float a0 = __builtin_exp2f(m_run[tt] - m);
            const float a1 = __builtin_exp2f(m1 - m);
            const float* ob = Ob + (hw * 16 + col) * 132;
            #pragma unroll
            for (int dt = 0; dt < 8; ++dt) {
                float4_t o1 = *(const float4_t*)(ob + dt * 16 + quad * 4);
                oacc[tt][dt] = oacc[tt][dt] * a0 + o1 * a1;
            }
            l_run[tt] = l_run[tt] * a0 + l1 * a1;
        }
    }

    // ---- epilogue (split 0 only): O[q][h][dim=dt*16+quad*4+r] = oacc/l ----
    if (split == 0) {
        #pragma unroll
        for (int tt = 0; tt < 2; ++tt) {
            const float inv_l = 1.0f / l_run[tt];
            float* op = O + ((long)qq[tt] * NH + h) * HD + quad * 4;
            #pragma unroll
            for (int dt = 0; dt < 8; ++dt) {
                float4_t ov;
                #pragma unroll
                for (int r = 0; r < 4; ++r) ov[r] = oacc[tt][dt][r] * inv_l;
                *(float4_t*)(op + dt * 16) = ov;
            }
        }
    }
}

extern "C" void kernel_launch(void* const* d_in, const int* in_sizes, int n_in,
                              void* d_out, int out_size, void* d_ws, size_t ws_size,
                              hipStream_t stream) {
    const float* Q  = (const float*)d_in[0];
    const float* K  = (const float*)d_in[1];
    const float* V  = (const float*)d_in[2];
    const int*   cu = (const int*)d_in[3];
    float*       O  = (float*)d_out;
    dim3 grid(T_TOK / 32, NG);
    attn_fwd<<<grid, 512, 0, stream>>>(Q, K, V, cu, O);
}